// Round 3
// baseline (70.299 us; speedup 1.0000x reference)
//
#include <hip/hip_runtime.h>
#include <math.h>

#define NQ 9
#define NREPS 2
#define NB 512            // 2^NQ amplitudes
#define NSIMS (16*28*28)  // 12544

// ---------------- compile-time linear algebra of the CNOT ring ----------------
__host__ __device__ constexpr int csigma(int b) {
    for (int c = NQ - 1; c >= 0; --c) {
        const int t  = (c + 1) % NQ;
        const int pc = NQ - 1 - c;
        const int pt = NQ - 1 - t;
        b ^= ((b >> pc) & 1) << pt;
    }
    return b;
}
__host__ __device__ constexpr int csig2(int b) { return csigma(csigma(b)); }

// basis images of sigma^2 (v(b) = XOR over set bits of b)
constexpr int VB_[6] = { csig2(1<<0), csig2(1<<1), csig2(1<<2),
                         csig2(1<<3), csig2(1<<4), csig2(1<<5) };
constexpr int VR_[8] = { csig2(0<<6), csig2(1<<6), csig2(2<<6), csig2(3<<6),
                         csig2(4<<6), csig2(5<<6), csig2(6<<6), csig2(7<<6) };

// ---------------- per-call tables (weight-dependent only) ----------------
// Bt[i][lane][r] = sin(Theta(b | m_i) - Theta(b & ~m_i)),  b = (r<<6)|lane
// symmetric under b -> b^m_i, so out_i = sum_{ALL b} m_b * m_{b^m_i} * B_i[b]
__device__ float g_Bt[NQ][64][8];

__global__ void quanv_setup(const float* __restrict__ w) {
    __shared__ float Th[NB];
    const int b = threadIdx.x;
    if (b < NB) {
        float th = 0.f;
        int cur = b;
        #pragma unroll
        for (int l = NREPS - 1; l >= 0; --l) {
            cur = csigma(cur);
            #pragma unroll
            for (int q = 0; q < NQ; ++q) {
                const float wq = 0.5f * w[l * NQ + q];
                th += ((cur >> (NQ - 1 - q)) & 1) ? wq : -wq;
            }
        }
        th -= 1.5707963267948966f * (float)__popc((unsigned)cur);
        Th[b] = th;
    }
    __syncthreads();
    if (b < NB) {
        #pragma unroll
        for (int i = 0; i < NQ; ++i) {
            const int m = 1 << (NQ - 1 - i);
            const float d = Th[b | m] - Th[b & ~m];
            g_Bt[i][b & 63][b >> 6] = sinf(d);
        }
    }
}

// ---------------- cross-lane helpers ----------------
template<int CTRL>
__device__ __forceinline__ float dppmov(float x) {
    return __int_as_float(__builtin_amdgcn_update_dpp(
        0, __float_as_int(x), CTRL, 0xF, 0xF, true));
}
template<int OFF>
__device__ __forceinline__ float swzx(float x) {
    return __int_as_float(__builtin_amdgcn_ds_swizzle(__float_as_int(x), OFF));
}
template<int P>
__device__ __forceinline__ float lane_xor(float x) {
    if constexpr (P == 0) return dppmov<0xB1>(x);      // quad_perm {1,0,3,2}
    else if constexpr (P == 1) return dppmov<0x4E>(x); // quad_perm {2,3,0,1}
    else if constexpr (P == 2) return swzx<0x101F>(x); // ds_swizzle xor 4
    else if constexpr (P == 3) return dppmov<0x128>(x);// row_ror:8 == xor 8
    else if constexpr (P == 4) return swzx<0x401F>(x); // ds_swizzle xor 16
    else return __shfl_xor(x, 32, 64);                 // cross-half
}
// full-wave sum via DPP; result valid in lane 63
__device__ __forceinline__ float wave_reduce(float v) {
    v += dppmov<0x111>(v);  // row_shr:1
    v += dppmov<0x112>(v);  // row_shr:2
    v += dppmov<0x114>(v);  // row_shr:4
    v += dppmov<0x118>(v);  // row_shr:8
    v += dppmov<0x142>(v);  // row_bcast:15
    v += dppmov<0x143>(v);  // row_bcast:31
    return v;
}

// ---------------- main: one wave per simulation ----------------
__global__ __launch_bounds__(256) void quanv_main(
    const float* __restrict__ x,   // [16][28][28]
    float* __restrict__ out)       // [16][9][28][28]
{
    const int tid  = blockIdx.x * blockDim.x + threadIdx.x;
    const int lane = threadIdx.x & 63;
    const int sim  = tid >> 6;          // grid exact: 3136*4 == 12544
    const int ox  = sim % 28;
    const int oy  = (sim / 28) % 28;
    const int img = sim / 784;

    // 9 patch half-angle cos/sin; a in [0,1) -> fast v_sin path
    float cq[NQ], sq[NQ];
    #pragma unroll
    for (int q = 0; q < NQ; ++q) {
        const int ky = q / 3, kx = q % 3;
        const int y  = oy + ky - 1;
        const int xx = ox + kx - 1;
        float a = 0.f;
        if (y >= 0 && y < 28 && xx >= 0 && xx < 28)
            a = x[img * 784 + y * 28 + xx];
        const float h = 0.5f * a;
        sq[q] = __sinf(h);
        cq[q] = __cosf(h);
    }

    // lane part of v = sigma^2(b)
    const int VL = ((lane & 1)  ? VB_[0] : 0) ^ ((lane & 2)  ? VB_[1] : 0)
                 ^ ((lane & 4)  ? VB_[2] : 0) ^ ((lane & 8)  ? VB_[3] : 0)
                 ^ ((lane & 16) ? VB_[4] : 0) ^ ((lane & 32) ? VB_[5] : 0);

    float P0[NQ], P1[NQ];
    #pragma unroll
    for (int q = 0; q < NQ; ++q) {
        const bool bit = (VL >> (NQ - 1 - q)) & 1;
        P0[q] = bit ? sq[q] : cq[q];
        P1[q] = bit ? cq[q] : sq[q];
    }

    // real magnitudes m[b], b = (r<<6)|lane  (VR_[r] selects are compile-time)
    float m[8];
    #pragma unroll
    for (int r = 0; r < 8; ++r) {
        float p = ((VR_[r] >> (NQ - 1)) & 1) ? P1[0] : P0[0];
        #pragma unroll
        for (int q = 1; q < NQ; ++q)
            p *= ((VR_[r] >> (NQ - 1 - q)) & 1) ? P1[q] : P0[q];
        m[r] = p;
    }

    float e[NQ];

    // lane-bit qubits i=3..8 (mask bit P = 8-i):
    // e[i] = sum over all lanes/r of m * m_partner * B  (B symmetric -> no sign)
#define EXPQ(i, P)                                                   \
    {                                                                \
        const float4 blo = *(const float4*)(&g_Bt[i][lane][0]);      \
        const float4 bhi = *(const float4*)(&g_Bt[i][lane][4]);      \
        const float B_[8] = { blo.x, blo.y, blo.z, blo.w,            \
                              bhi.x, bhi.y, bhi.z, bhi.w };          \
        float acc = 0.f;                                             \
        _Pragma("unroll")                                            \
        for (int r = 0; r < 8; ++r) {                                \
            const float gm = lane_xor<P>(m[r]);                      \
            acc = fmaf(m[r] * gm, B_[r], acc);                       \
        }                                                            \
        e[i] = acc;                                                  \
    }
    EXPQ(8, 0)
    EXPQ(7, 1)
    EXPQ(6, 2)
    EXPQ(5, 3)
    EXPQ(4, 4)
    EXPQ(3, 5)
#undef EXPQ

    // register-bit qubits i=0..2 (mask bit rb = 2-i in r): pairs within lane
    #pragma unroll
    for (int i = 0; i < 3; ++i) {
        const int rb = 2 - i;
        const float4 blo = *(const float4*)(&g_Bt[i][lane][0]);
        const float4 bhi = *(const float4*)(&g_Bt[i][lane][4]);
        const float B_[8] = { blo.x, blo.y, blo.z, blo.w,
                              bhi.x, bhi.y, bhi.z, bhi.w };
        float acc = 0.f;
        #pragma unroll
        for (int r = 0; r < 8; ++r)
            acc = fmaf(m[r] * m[r ^ (1 << rb)], B_[r], acc);
        e[i] = acc;
    }

    // reduce the 9 partials across the wave (DPP; lane 63 holds the sums)
    #pragma unroll
    for (int i = 0; i < NQ; ++i)
        e[i] = wave_reduce(e[i]);

    if (lane == 63) {
        float* o = out + img * (NQ * 784) + oy * 28 + ox;
        #pragma unroll
        for (int i = 0; i < NQ; ++i)
            o[i * 784] = e[i];
    }
}

extern "C" void kernel_launch(void* const* d_in, const int* in_sizes, int n_in,
                              void* d_out, int out_size, void* d_ws, size_t ws_size,
                              hipStream_t stream) {
    const float* x = (const float*)d_in[0];   // 16*1*28*28 fp32
    const float* w = (const float*)d_in[1];   // NREPS*NQ fp32
    float* out = (float*)d_out;               // 16*9*28*28 fp32
    (void)d_ws; (void)ws_size; (void)in_sizes; (void)n_in; (void)out_size;

    quanv_setup<<<1, NB, 0, stream>>>(w);
    quanv_main<<<NSIMS / 4, 256, 0, stream>>>(x, out);  // 4 waves/block
}

// Round 5
// 69.259 us; speedup vs baseline: 1.0150x; 1.0150x over previous
//
#include <hip/hip_runtime.h>
#include <math.h>

#define NQ 9
#define NREPS 2
#define NB 512            // 2^NQ amplitudes
#define NSIMS (16*28*28)  // 12544

// ---------------- compile-time linear algebra of the CNOT ring ----------------
__host__ __device__ constexpr int csigma(int b) {
    for (int c = NQ - 1; c >= 0; --c) {
        const int t  = (c + 1) % NQ;
        const int pc = NQ - 1 - c;
        const int pt = NQ - 1 - t;
        b ^= ((b >> pc) & 1) << pt;
    }
    return b;
}
__host__ __device__ constexpr int csig2(int b) { return csigma(csigma(b)); }

// basis images of sigma^2 (v(b) = XOR over set bits of b)
constexpr int VB_[6] = { csig2(1<<0), csig2(1<<1), csig2(1<<2),
                         csig2(1<<3), csig2(1<<4), csig2(1<<5) };
constexpr int VR_[8] = { csig2(0<<6), csig2(1<<6), csig2(2<<6), csig2(3<<6),
                         csig2(4<<6), csig2(5<<6), csig2(6<<6), csig2(7<<6) };

// ---------------- cross-lane helpers ----------------
template<int CTRL>
__device__ __forceinline__ float dppmov(float x) {
    return __int_as_float(__builtin_amdgcn_update_dpp(
        0, __float_as_int(x), CTRL, 0xF, 0xF, true));
}
template<int OFF>
__device__ __forceinline__ int swzx_i(int x) {
    return __builtin_amdgcn_ds_swizzle(x, OFF);
}
// full-wave sum via DPP; result valid in lane 63
__device__ __forceinline__ float wave_reduce(float v) {
    v += dppmov<0x111>(v);  // row_shr:1
    v += dppmov<0x112>(v);  // row_shr:2
    v += dppmov<0x114>(v);  // row_shr:4
    v += dppmov<0x118>(v);  // row_shr:8
    v += dppmov<0x142>(v);  // row_bcast:15
    v += dppmov<0x143>(v);  // row_bcast:31
    return v;
}

// ---------------- f16x2 pack/unpack for single-b32 exchanges ----------------
typedef __fp16 h2_t __attribute__((ext_vector_type(2)));
__device__ __forceinline__ int packf16(float a, float b) {
    h2_t h = __builtin_amdgcn_cvt_pkrtz(a, b);
    int i; __builtin_memcpy(&i, &h, 4); return i;
}
__device__ __forceinline__ float2 unpackf16(int i) {
    h2_t h; __builtin_memcpy(&h, &i, 4);
    return make_float2((float)h.x, (float)h.y);
}

// ---------------- fused kernel: one wave per simulation ----------------
__global__ __launch_bounds__(256) void quanv_fused(
    const float* __restrict__ x,   // [16][28][28]
    const float* __restrict__ w,   // [NREPS][NQ]
    float* __restrict__ out)       // [16][9][28][28]
{
    // ---- per-block phase table: T[b] = (cos Theta(b), sin Theta(b)) ----
    __shared__ float2 T[NB];
    {
        const int t = threadIdx.x;
        #pragma unroll
        for (int bb = t; bb < NB; bb += 256) {
            float th = 0.f;
            int cur = bb;
            #pragma unroll
            for (int l = NREPS - 1; l >= 0; --l) {
                cur = csigma(cur);
                #pragma unroll
                for (int q = 0; q < NQ; ++q) {
                    const float wq = 0.5f * w[l * NQ + q];
                    th += ((cur >> (NQ - 1 - q)) & 1) ? wq : -wq;
                }
            }
            th -= 1.5707963267948966f * (float)__popc((unsigned)cur);
            float s, c;
            sincosf(th, &s, &c);
            T[bb] = make_float2(c, s);
        }
    }
    __syncthreads();

    const int tid  = blockIdx.x * blockDim.x + threadIdx.x;
    const int lane = threadIdx.x & 63;
    const int sim  = tid >> 6;          // grid exact: 3136*4 == 12544
    const int ox  = sim % 28;
    const int oy  = (sim / 28) % 28;
    const int img = sim / 784;

    // 9 patch half-angle cos/sin; h in [0,0.5) -> fast native path
    float cq[NQ], sq[NQ];
    #pragma unroll
    for (int q = 0; q < NQ; ++q) {
        const int ky = q / 3, kx = q % 3;
        const int y  = oy + ky - 1;
        const int xx = ox + kx - 1;
        float a = 0.f;
        if (y >= 0 && y < 28 && xx >= 0 && xx < 28)
            a = x[img * 784 + y * 28 + xx];
        const float h = 0.5f * a;
        sq[q] = __sinf(h);
        cq[q] = __cosf(h);
    }

    // lane part of v = sigma^2(b)
    const int VL = ((lane & 1)  ? VB_[0] : 0) ^ ((lane & 2)  ? VB_[1] : 0)
                 ^ ((lane & 4)  ? VB_[2] : 0) ^ ((lane & 8)  ? VB_[3] : 0)
                 ^ ((lane & 16) ? VB_[4] : 0) ^ ((lane & 32) ? VB_[5] : 0);

    float P0[NQ], P1[NQ];
    #pragma unroll
    for (int q = 0; q < NQ; ++q) {
        const bool bit = (VL >> (NQ - 1 - q)) & 1;
        P0[q] = bit ? sq[q] : cq[q];
        P1[q] = bit ? cq[q] : sq[q];
    }

    // amplitudes f[b] = m * (cosT, sinT), b = (r<<6)|lane; pk = f16x2 pack
    float fre[8], fim[8];
    int   pk[8];
    #pragma unroll
    for (int r = 0; r < 8; ++r) {
        float m = ((VR_[r] >> (NQ - 1)) & 1) ? P1[0] : P0[0];
        #pragma unroll
        for (int q = 1; q < NQ; ++q)
            m *= ((VR_[r] >> (NQ - 1 - q)) & 1) ? P1[q] : P0[q];
        const float2 t = T[(r << 6) | lane];
        fre[r] = m * t.x;
        fim[r] = m * t.y;
        pk[r]  = packf16(fre[r], fim[r]);
    }

    // expectations out_i = 2*Im sum_{bit_i=0} conj(f[b]) f[b^mask_i]
    float e[NQ];

    // DPP qubits (lane-bit P in {0,1,3}): f32 exchange on the VALU pipe
#define EXPQ_DPP(i, P, CTRL)                                       \
    {                                                              \
        const float sign = ((lane >> (P)) & 1) ? -1.f : 1.f;       \
        float acc = 0.f;                                           \
        _Pragma("unroll")                                          \
        for (int r = 0; r < 8; ++r) {                              \
            const float gre = dppmov<CTRL>(fre[r]);                \
            const float gim = dppmov<CTRL>(fim[r]);                \
            acc += fre[r] * gim - fim[r] * gre;                    \
        }                                                          \
        e[i] = sign * acc;                                         \
    }
    EXPQ_DPP(8, 0, 0xB1)   // quad_perm {1,0,3,2}  : xor 1
    EXPQ_DPP(7, 1, 0x4E)   // quad_perm {2,3,0,1}  : xor 2
    EXPQ_DPP(5, 3, 0x128)  // row_ror:8            : xor 8
#undef EXPQ_DPP

    // DS qubits (lane-bit P in {2,4}): single packed-b32 ds_swizzle
#define EXPQ_SWZ(i, P, OFF)                                        \
    {                                                              \
        const float sign = ((lane >> (P)) & 1) ? -1.f : 1.f;       \
        float acc = 0.f;                                           \
        _Pragma("unroll")                                          \
        for (int r = 0; r < 8; ++r) {                              \
            const float2 g = unpackf16(swzx_i<OFF>(pk[r]));        \
            acc += fre[r] * g.y - fim[r] * g.x;                    \
        }                                                          \
        e[i] = sign * acc;                                         \
    }
    EXPQ_SWZ(6, 2, 0x101F)  // xor 4
    EXPQ_SWZ(4, 4, 0x401F)  // xor 16
#undef EXPQ_SWZ

    // cross-half qubit (lane-bit 5): single packed-b32 shfl_xor 32
    {
        const float sign = ((lane >> 5) & 1) ? -1.f : 1.f;
        float acc = 0.f;
        #pragma unroll
        for (int r = 0; r < 8; ++r) {
            const float2 g = unpackf16(__shfl_xor(pk[r], 32, 64));
            acc += fre[r] * g.y - fim[r] * g.x;
        }
        e[3] = sign * acc;
    }

    // register-bit qubits i=0..2 (mask bit rb = 2-i in r): pairs within lane
    #pragma unroll
    for (int i = 0; i < 3; ++i) {
        const int rb = 2 - i;
        float acc = 0.f;
        #pragma unroll
        for (int r = 0; r < 8; ++r) {
            if (!((r >> rb) & 1)) {
                const int r1 = r | (1 << rb);
                acc += fre[r] * fim[r1] - fim[r] * fre[r1];
            }
        }
        e[i] = 2.f * acc;
    }

    // reduce the 9 partials across the wave (DPP; lane 63 holds the sums)
    #pragma unroll
    for (int i = 0; i < NQ; ++i)
        e[i] = wave_reduce(e[i]);

    if (lane == 63) {
        float* o = out + img * (NQ * 784) + oy * 28 + ox;
        #pragma unroll
        for (int i = 0; i < NQ; ++i)
            o[i * 784] = e[i];
    }
}

extern "C" void kernel_launch(void* const* d_in, const int* in_sizes, int n_in,
                              void* d_out, int out_size, void* d_ws, size_t ws_size,
                              hipStream_t stream) {
    const float* x = (const float*)d_in[0];   // 16*1*28*28 fp32
    const float* w = (const float*)d_in[1];   // NREPS*NQ fp32
    float* out = (float*)d_out;               // 16*9*28*28 fp32
    (void)d_ws; (void)ws_size; (void)in_sizes; (void)n_in; (void)out_size;

    quanv_fused<<<NSIMS / 4, 256, 0, stream>>>(x, w, out);  // 4 waves/block
}

// Round 6
// 68.470 us; speedup vs baseline: 1.0267x; 1.0115x over previous
//
#include <hip/hip_runtime.h>
#include <math.h>

#define NQ 9
#define NREPS 2
#define NB 512            // 2^NQ amplitudes
#define NSIMS (16*28*28)  // 12544

// ---------------- compile-time linear algebra of the CNOT ring ----------------
__host__ __device__ constexpr int csigma(int b) {
    for (int c = NQ - 1; c >= 0; --c) {
        const int t  = (c + 1) % NQ;
        const int pc = NQ - 1 - c;
        const int pt = NQ - 1 - t;
        b ^= ((b >> pc) & 1) << pt;
    }
    return b;
}
__host__ __device__ constexpr int csig2(int b) { return csigma(csigma(b)); }

// basis images of sigma^2 (v(b) = XOR over set bits of b)
constexpr int VB_[6] = { csig2(1<<0), csig2(1<<1), csig2(1<<2),
                         csig2(1<<3), csig2(1<<4), csig2(1<<5) };
constexpr int VR_[8] = { csig2(0<<6), csig2(1<<6), csig2(2<<6), csig2(3<<6),
                         csig2(4<<6), csig2(5<<6), csig2(6<<6), csig2(7<<6) };

// ---------------- cross-lane helpers ----------------
template<int CTRL>
__device__ __forceinline__ float dppmov(float x) {
    return __int_as_float(__builtin_amdgcn_update_dpp(
        0, __float_as_int(x), CTRL, 0xF, 0xF, true));
}
template<int OFF>
__device__ __forceinline__ int swzx_i(int x) {
    return __builtin_amdgcn_ds_swizzle(x, OFF);
}
// full-wave sum via DPP; result valid in lane 63
__device__ __forceinline__ float wave_reduce(float v) {
    v += dppmov<0x111>(v);  // row_shr:1
    v += dppmov<0x112>(v);  // row_shr:2
    v += dppmov<0x114>(v);  // row_shr:4
    v += dppmov<0x118>(v);  // row_shr:8
    v += dppmov<0x142>(v);  // row_bcast:15
    v += dppmov<0x143>(v);  // row_bcast:31
    return v;
}

// ---------------- f16x2 pack/unpack for single-b32 exchanges ----------------
typedef __fp16 h2_t __attribute__((ext_vector_type(2)));
__device__ __forceinline__ int packf16(float a, float b) {
    h2_t h = __builtin_amdgcn_cvt_pkrtz(a, b);
    int i; __builtin_memcpy(&i, &h, 4); return i;
}
__device__ __forceinline__ float2 unpackf16(int i) {
    h2_t h; __builtin_memcpy(&h, &i, 4);
    return make_float2((float)h.x, (float)h.y);
}

// ---------------- fused kernel: one wave per simulation ----------------
__global__ __launch_bounds__(256) void quanv_fused(
    const float* __restrict__ x,   // [16][28][28]
    const float* __restrict__ w,   // [NREPS][NQ]
    float* __restrict__ out)       // [16][9][28][28]
{
    // ---- per-block phase table: T[b] = (cos Theta(b), sin Theta(b)) ----
    // |Theta| <= 2*9*pi/2 + 9*pi/2 ~ 33 rad: well within native v_sin range.
    __shared__ float2 T[NB];
    {
        const int t = threadIdx.x;
        #pragma unroll
        for (int bb = t; bb < NB; bb += 256) {
            float th = 0.f;
            int cur = bb;
            #pragma unroll
            for (int l = NREPS - 1; l >= 0; --l) {
                cur = csigma(cur);
                #pragma unroll
                for (int q = 0; q < NQ; ++q) {
                    const float wq = 0.5f * w[l * NQ + q];
                    th += ((cur >> (NQ - 1 - q)) & 1) ? wq : -wq;
                }
            }
            th -= 1.5707963267948966f * (float)__popc((unsigned)cur);
            float s, c;
            __sincosf(th, &s, &c);   // native path — the r5 slow-sincosf fix
            T[bb] = make_float2(c, s);
        }
    }
    __syncthreads();

    const int tid  = blockIdx.x * blockDim.x + threadIdx.x;
    const int lane = threadIdx.x & 63;
    const int sim  = tid >> 6;          // grid exact: 3136*4 == 12544
    const int ox  = sim % 28;
    const int oy  = (sim / 28) % 28;
    const int img = sim / 784;

    // 9 patch half-angle cos/sin; h in [0,0.5) -> fast native path
    float cq[NQ], sq[NQ];
    #pragma unroll
    for (int q = 0; q < NQ; ++q) {
        const int ky = q / 3, kx = q % 3;
        const int y  = oy + ky - 1;
        const int xx = ox + kx - 1;
        float a = 0.f;
        if (y >= 0 && y < 28 && xx >= 0 && xx < 28)
            a = x[img * 784 + y * 28 + xx];
        const float h = 0.5f * a;
        sq[q] = __sinf(h);
        cq[q] = __cosf(h);
    }

    // lane part of v = sigma^2(b)
    const int VL = ((lane & 1)  ? VB_[0] : 0) ^ ((lane & 2)  ? VB_[1] : 0)
                 ^ ((lane & 4)  ? VB_[2] : 0) ^ ((lane & 8)  ? VB_[3] : 0)
                 ^ ((lane & 16) ? VB_[4] : 0) ^ ((lane & 32) ? VB_[5] : 0);

    float P0[NQ], P1[NQ];
    #pragma unroll
    for (int q = 0; q < NQ; ++q) {
        const bool bit = (VL >> (NQ - 1 - q)) & 1;
        P0[q] = bit ? sq[q] : cq[q];
        P1[q] = bit ? cq[q] : sq[q];
    }

    // amplitudes f[b] = m * (cosT, sinT), b = (r<<6)|lane; pk = f16x2 pack
    float fre[8], fim[8];
    int   pk[8];
    #pragma unroll
    for (int r = 0; r < 8; ++r) {
        float m = ((VR_[r] >> (NQ - 1)) & 1) ? P1[0] : P0[0];
        #pragma unroll
        for (int q = 1; q < NQ; ++q)
            m *= ((VR_[r] >> (NQ - 1 - q)) & 1) ? P1[q] : P0[q];
        const float2 t = T[(r << 6) | lane];
        fre[r] = m * t.x;
        fim[r] = m * t.y;
        pk[r]  = packf16(fre[r], fim[r]);
    }

    // expectations out_i = 2*Im sum_{bit_i=0} conj(f[b]) f[b^mask_i]
    float e[NQ];

    // DPP qubits (lane-bit P in {0,1,3}): f32 exchange on the VALU pipe
#define EXPQ_DPP(i, P, CTRL)                                       \
    {                                                              \
        const float sign = ((lane >> (P)) & 1) ? -1.f : 1.f;       \
        float acc = 0.f;                                           \
        _Pragma("unroll")                                          \
        for (int r = 0; r < 8; ++r) {                              \
            const float gre = dppmov<CTRL>(fre[r]);                \
            const float gim = dppmov<CTRL>(fim[r]);                \
            acc += fre[r] * gim - fim[r] * gre;                    \
        }                                                          \
        e[i] = sign * acc;                                         \
    }
    EXPQ_DPP(8, 0, 0xB1)   // quad_perm {1,0,3,2}  : xor 1
    EXPQ_DPP(7, 1, 0x4E)   // quad_perm {2,3,0,1}  : xor 2
    EXPQ_DPP(5, 3, 0x128)  // row_ror:8            : xor 8
#undef EXPQ_DPP

    // DS qubits (lane-bit P in {2,4}): single packed-b32 ds_swizzle
#define EXPQ_SWZ(i, P, OFF)                                        \
    {                                                              \
        const float sign = ((lane >> (P)) & 1) ? -1.f : 1.f;       \
        float acc = 0.f;                                           \
        _Pragma("unroll")                                          \
        for (int r = 0; r < 8; ++r) {                              \
            const float2 g = unpackf16(swzx_i<OFF>(pk[r]));        \
            acc += fre[r] * g.y - fim[r] * g.x;                    \
        }                                                          \
        e[i] = sign * acc;                                         \
    }
    EXPQ_SWZ(6, 2, 0x101F)  // xor 4
    EXPQ_SWZ(4, 4, 0x401F)  // xor 16
#undef EXPQ_SWZ

    // cross-half qubit (lane-bit 5): single packed-b32 shfl_xor 32
    {
        const float sign = ((lane >> 5) & 1) ? -1.f : 1.f;
        float acc = 0.f;
        #pragma unroll
        for (int r = 0; r < 8; ++r) {
            const float2 g = unpackf16(__shfl_xor(pk[r], 32, 64));
            acc += fre[r] * g.y - fim[r] * g.x;
        }
        e[3] = sign * acc;
    }

    // register-bit qubits i=0..2 (mask bit rb = 2-i in r): pairs within lane
    #pragma unroll
    for (int i = 0; i < 3; ++i) {
        const int rb = 2 - i;
        float acc = 0.f;
        #pragma unroll
        for (int r = 0; r < 8; ++r) {
            if (!((r >> rb) & 1)) {
                const int r1 = r | (1 << rb);
                acc += fre[r] * fim[r1] - fim[r] * fre[r1];
            }
        }
        e[i] = 2.f * acc;
    }

    // reduce the 9 partials across the wave (DPP; lane 63 holds the sums)
    #pragma unroll
    for (int i = 0; i < NQ; ++i)
        e[i] = wave_reduce(e[i]);

    if (lane == 63) {
        float* o = out + img * (NQ * 784) + oy * 28 + ox;
        #pragma unroll
        for (int i = 0; i < NQ; ++i)
            o[i * 784] = e[i];
    }
}

extern "C" void kernel_launch(void* const* d_in, const int* in_sizes, int n_in,
                              void* d_out, int out_size, void* d_ws, size_t ws_size,
                              hipStream_t stream) {
    const float* x = (const float*)d_in[0];   // 16*1*28*28 fp32
    const float* w = (const float*)d_in[1];   // NREPS*NQ fp32
    float* out = (float*)d_out;               // 16*9*28*28 fp32
    (void)d_ws; (void)ws_size; (void)in_sizes; (void)n_in; (void)out_size;

    quanv_fused<<<NSIMS / 4, 256, 0, stream>>>(x, w, out);  // 4 waves/block
}

// Round 7
// 68.112 us; speedup vs baseline: 1.0321x; 1.0053x over previous
//
#include <hip/hip_runtime.h>
#include <math.h>

#define NQ 9
#define NREPS 2
#define NB 512            // 2^NQ amplitudes
#define NSIMS (16*28*28)  // 12544

// ---------------- compile-time linear algebra of the CNOT ring ----------------
__host__ __device__ constexpr int csigma(int b) {
    for (int c = NQ - 1; c >= 0; --c) {
        const int t  = (c + 1) % NQ;
        const int pc = NQ - 1 - c;
        const int pt = NQ - 1 - t;
        b ^= ((b >> pc) & 1) << pt;
    }
    return b;
}
__host__ __device__ constexpr int csig2(int b) { return csigma(csigma(b)); }

// lane-bit basis images of sigma^2 (VL = XOR over set lane bits)
constexpr int VB_[6] = { csig2(1<<0), csig2(1<<1), csig2(1<<2),
                         csig2(1<<3), csig2(1<<4), csig2(1<<5) };
// register-bit basis images (hand-derived, checked against csig2):
// G0=sig2(e6)={p4,p6}->qubits{4,2}, G1=sig2(e7)={p5,p7}->qubits{3,1},
// G2=sig2(e8)={p6,p8}->qubits{2,0}
static_assert(csig2(1<<6) == ((1<<4)|(1<<6)), "G0");
static_assert(csig2(1<<7) == ((1<<5)|(1<<7)), "G1");
static_assert(csig2(1<<8) == ((1<<6)|(1<<8)), "G2");

// ---------------- per-call table (weight-dependent only) ----------------
__device__ float2 g_T[NB];   // {cos Theta(b), sin Theta(b)}

__global__ void quanv_setup(const float* __restrict__ w) {
    const int b = threadIdx.x;
    if (b >= NB) return;
    float th = 0.f;
    int cur = b;
    #pragma unroll
    for (int l = NREPS - 1; l >= 0; --l) {
        cur = csigma(cur);
        #pragma unroll
        for (int q = 0; q < NQ; ++q) {
            const float wq = 0.5f * w[l * NQ + q];
            th += ((cur >> (NQ - 1 - q)) & 1) ? wq : -wq;
        }
    }
    th -= 1.5707963267948966f * (float)__popc((unsigned)cur);
    float s, c;
    __sincosf(th, &s, &c);   // |th| <= ~33 rad, native path is fine
    g_T[b] = make_float2(c, s);
}

// ---------------- cross-lane helpers ----------------
template<int CTRL>
__device__ __forceinline__ float dppmov(float x) {
    return __int_as_float(__builtin_amdgcn_update_dpp(
        0, __float_as_int(x), CTRL, 0xF, 0xF, true));
}
template<int OFF>
__device__ __forceinline__ int swzx_i(int x) {
    return __builtin_amdgcn_ds_swizzle(x, OFF);
}
// full-wave sum via DPP; result valid in lane 63
__device__ __forceinline__ float wave_reduce(float v) {
    v += dppmov<0x111>(v);  // row_shr:1
    v += dppmov<0x112>(v);  // row_shr:2
    v += dppmov<0x114>(v);  // row_shr:4
    v += dppmov<0x118>(v);  // row_shr:8
    v += dppmov<0x142>(v);  // row_bcast:15
    v += dppmov<0x143>(v);  // row_bcast:31
    return v;
}

// ---------------- f16x2 pack/unpack for single-b32 exchanges ----------------
typedef __fp16 h2_t __attribute__((ext_vector_type(2)));
__device__ __forceinline__ int packf16(float a, float b) {
    h2_t h = __builtin_amdgcn_cvt_pkrtz(a, b);
    int i; __builtin_memcpy(&i, &h, 4); return i;
}
__device__ __forceinline__ float2 unpackf16(int i) {
    h2_t h; __builtin_memcpy(&h, &i, 4);
    return make_float2((float)h.x, (float)h.y);
}

// ---------------- main: one wave per simulation ----------------
__global__ __launch_bounds__(256) void quanv_main(
    const float* __restrict__ x,   // [16][28][28]
    float* __restrict__ out)       // [16][9][28][28]
{
    const int tid  = blockIdx.x * blockDim.x + threadIdx.x;
    const int lane = threadIdx.x & 63;
    const int sim  = tid >> 6;          // grid exact: 3136*4 == 12544
    const int ox  = sim % 28;
    const int oy  = (sim / 28) % 28;
    const int img = sim / 784;

    // 9 patch half-angle cos/sin; h in [0,0.5) -> native path
    float cq[NQ], sq[NQ];
    #pragma unroll
    for (int q = 0; q < NQ; ++q) {
        const int ky = q / 3, kx = q % 3;
        const int y  = oy + ky - 1;
        const int xx = ox + kx - 1;
        float a = 0.f;
        if (y >= 0 && y < 28 && xx >= 0 && xx < 28)
            a = x[img * 784 + y * 28 + xx];
        const float h = 0.5f * a;
        sq[q] = __sinf(h);
        cq[q] = __cosf(h);
    }

    // lane part of v = sigma^2(b)
    const int VL = ((lane & 1)  ? VB_[0] : 0) ^ ((lane & 2)  ? VB_[1] : 0)
                 ^ ((lane & 4)  ? VB_[2] : 0) ^ ((lane & 8)  ? VB_[3] : 0)
                 ^ ((lane & 16) ? VB_[4] : 0) ^ ((lane & 32) ? VB_[5] : 0);

    // P0[q] = factor when sigma^2(b) bit q equals VL bit q; P1 = flipped
    float P0[NQ], P1[NQ];
    #pragma unroll
    for (int q = 0; q < NQ; ++q) {
        const bool bit = (VL >> (NQ - 1 - q)) & 1;
        P0[q] = bit ? sq[q] : cq[q];
        P1[q] = bit ? cq[q] : sq[q];
    }

    // ---- Gray-code m-product (23 muls instead of 64) ----
    // register-bit contributions: r bit0 flips qubits {4,2}; bit1 flips {3,1};
    // bit2 flips {2,0}.  Classes: const {5,6,7,8}; {4}<-b0; {3,1}<-b1;
    // {2}<-b0^b2; {0}<-b2.
    const float K   = P0[5] * P0[6] * P0[7] * P0[8];
    const float Fb0 = P0[3] * P0[1], Fb1 = P1[3] * P1[1];
    const float T2_0 = K * Fb0, T2_1 = K * Fb1;                 // index: par2 (r bit1)
    const float T24_00 = T2_0 * P0[0], T24_01 = T2_0 * P1[0];   // x par4 (r bit2)
    const float T24_10 = T2_1 * P0[0], T24_11 = T2_1 * P1[0];
    // PP[par1][par4] = P(q4, par1) * P(q2, par1^par4)
    const float PP_00 = P0[4] * P0[2], PP_01 = P0[4] * P1[2];
    const float PP_10 = P1[4] * P1[2], PP_11 = P1[4] * P0[2];
    const float T24_[2][2] = { {T24_00, T24_01}, {T24_10, T24_11} };
    const float PP_[2][2]  = { {PP_00, PP_01}, {PP_10, PP_11} };

    // amplitudes f[b] = m * (cosT, sinT), b = (r<<6)|lane; pk = f16x2 pack
    float fre[8], fim[8];
    int   pk[8];
    #pragma unroll
    for (int r = 0; r < 8; ++r) {
        const int p1 = r & 1, p2 = (r >> 1) & 1, p4 = (r >> 2) & 1;
        const float m = T24_[p2][p4] * PP_[p1][p4];
        const float2 t = g_T[(r << 6) | lane];
        fre[r] = m * t.x;
        fim[r] = m * t.y;
        pk[r]  = packf16(fre[r], fim[r]);
    }

    // expectations out_i = 2*Im sum_{bit_i=0} conj(f[b]) f[b^mask_i]
    float e[NQ];

    // DPP qubits (lane-bit P in {0,1,3}): f32 exchange on the VALU pipe
#define EXPQ_DPP(i, P, CTRL)                                       \
    {                                                              \
        const float sign = ((lane >> (P)) & 1) ? -1.f : 1.f;       \
        float acc = 0.f;                                           \
        _Pragma("unroll")                                          \
        for (int r = 0; r < 8; ++r) {                              \
            const float gre = dppmov<CTRL>(fre[r]);                \
            const float gim = dppmov<CTRL>(fim[r]);                \
            acc += fre[r] * gim - fim[r] * gre;                    \
        }                                                          \
        e[i] = sign * acc;                                         \
    }
    EXPQ_DPP(8, 0, 0xB1)   // quad_perm {1,0,3,2}  : xor 1
    EXPQ_DPP(7, 1, 0x4E)   // quad_perm {2,3,0,1}  : xor 2
    EXPQ_DPP(5, 3, 0x128)  // row_ror:8            : xor 8
#undef EXPQ_DPP

    // DS qubits (lane-bit P in {2,4}): single packed-b32 ds_swizzle
#define EXPQ_SWZ(i, P, OFF)                                        \
    {                                                              \
        const float sign = ((lane >> (P)) & 1) ? -1.f : 1.f;       \
        float acc = 0.f;                                           \
        _Pragma("unroll")                                          \
        for (int r = 0; r < 8; ++r) {                              \
            const float2 g = unpackf16(swzx_i<OFF>(pk[r]));        \
            acc += fre[r] * g.y - fim[r] * g.x;                    \
        }                                                          \
        e[i] = sign * acc;                                         \
    }
    EXPQ_SWZ(6, 2, 0x101F)  // xor 4
    EXPQ_SWZ(4, 4, 0x401F)  // xor 16
#undef EXPQ_SWZ

    // cross-half qubit (lane-bit 5): single packed-b32 shfl_xor 32
    {
        const float sign = ((lane >> 5) & 1) ? -1.f : 1.f;
        float acc = 0.f;
        #pragma unroll
        for (int r = 0; r < 8; ++r) {
            const float2 g = unpackf16(__shfl_xor(pk[r], 32, 64));
            acc += fre[r] * g.y - fim[r] * g.x;
        }
        e[3] = sign * acc;
    }

    // register-bit qubits i=0..2 (mask bit rb = 2-i in r): pairs within lane
    #pragma unroll
    for (int i = 0; i < 3; ++i) {
        const int rb = 2 - i;
        float acc = 0.f;
        #pragma unroll
        for (int r = 0; r < 8; ++r) {
            if (!((r >> rb) & 1)) {
                const int r1 = r | (1 << rb);
                acc += fre[r] * fim[r1] - fim[r] * fre[r1];
            }
        }
        e[i] = 2.f * acc;
    }

    // reduce the 9 partials across the wave (DPP; lane 63 holds the sums)
    #pragma unroll
    for (int i = 0; i < NQ; ++i)
        e[i] = wave_reduce(e[i]);

    if (lane == 63) {
        float* o = out + img * (NQ * 784) + oy * 28 + ox;
        #pragma unroll
        for (int i = 0; i < NQ; ++i)
            o[i * 784] = e[i];
    }
}

extern "C" void kernel_launch(void* const* d_in, const int* in_sizes, int n_in,
                              void* d_out, int out_size, void* d_ws, size_t ws_size,
                              hipStream_t stream) {
    const float* x = (const float*)d_in[0];   // 16*1*28*28 fp32
    const float* w = (const float*)d_in[1];   // NREPS*NQ fp32
    float* out = (float*)d_out;               // 16*9*28*28 fp32
    (void)d_ws; (void)ws_size; (void)in_sizes; (void)n_in; (void)out_size;

    quanv_setup<<<1, NB, 0, stream>>>(w);
    quanv_main<<<NSIMS / 4, 256, 0, stream>>>(x, out);  // 4 waves/block
}